// Round 10
// baseline (299.877 us; speedup 1.0000x reference)
//
#include <hip/hip_runtime.h>
#include <math.h>

// ---------------------------------------------------------------------------
// Attn_14920716386547 R10 = R9 (184.2 us) + software-pipelined GEMMs.
// R9 analysis: gemm_qkv 48 us = ~2400 cyc/phase vs ~600 ideal (staging 585 +
// MFMA 466, overlappable). Not BW-bound (HBM 17%), not MFMA-bound (20%):
// global-load latency is naked on the critical path between barriers.
// R10: BH=1 GEMM K-loops prefetch tile k+1 into VGPRs during tile k's
// MFMA phase (VGPR 88->~120, occupancy unchanged). Attn untouched.
// ws (halves): Vth [0,4M) | Xh/Og overlay [4M,8M) | Wqkvh [8M,11M) |
//   Woh [11M,12M) (big path only). d_out: Qh|Kh scratch (dead before out).
// ---------------------------------------------------------------------------

typedef _Float16 f16x8 __attribute__((ext_vector_type(8)));
typedef _Float16 f16x4 __attribute__((ext_vector_type(4)));
typedef _Float16 f16x2 __attribute__((ext_vector_type(2)));
typedef __attribute__((ext_vector_type(4))) float f32x4;
typedef __attribute__((ext_vector_type(16))) float f32x16;

#define MFMA16(a, b, c) __builtin_amdgcn_mfma_f32_16x16x32_f16(a, b, c, 0, 0, 0)
#define MFMA32(a, b, c) __builtin_amdgcn_mfma_f32_32x32x16_f16(a, b, c, 0, 0, 0)
#define QSCALE 0.18033688f /* 0.125 * log2(e): attention runs in exp2 domain */

__device__ __forceinline__ f16x2 pk2(float x, float y) {
  return __builtin_bit_cast(f16x2, __builtin_amdgcn_cvt_pkrtz(x, y));
}

__device__ __forceinline__ f16x8 cvt8(const float* __restrict__ p) {
  float4 a = *(const float4*)p;
  float4 b = *(const float4*)(p + 4);
  f16x2 p0 = pk2(a.x, a.y), p1 = pk2(a.z, a.w);
  f16x2 p2 = pk2(b.x, b.y), p3 = pk2(b.z, b.w);
  f16x8 h;
  h[0] = p0[0]; h[1] = p0[1]; h[2] = p1[0]; h[3] = p1[1];
  h[4] = p2[0]; h[5] = p2[1]; h[6] = p3[0]; h[7] = p3[1];
  return h;
}

// ---- fp32 -> fp16 convert: X always; with grid=4096 also Wq|Wk|Wv|Wo ------
__global__ void convert_all(const float* __restrict__ X, const float* __restrict__ Wq,
                            const float* __restrict__ Wk, const float* __restrict__ Wv,
                            const float* __restrict__ Wo, _Float16* __restrict__ Xh,
                            _Float16* __restrict__ Wqkvh, _Float16* __restrict__ Woh) {
  size_t i = ((size_t)blockIdx.x * 256 + threadIdx.x) * 8;
  const float* src; _Float16* dst; size_t off;
  if (i < 4194304u)      { src = X;  dst = Xh;              off = i; }
  else if (i < 5242880u) { src = Wq; dst = Wqkvh;           off = i - 4194304u; }
  else if (i < 6291456u) { src = Wk; dst = Wqkvh + 1048576; off = i - 5242880u; }
  else if (i < 7340032u) { src = Wv; dst = Wqkvh + 2097152; off = i - 6291456u; }
  else                   { src = Wo; dst = Woh;             off = i - 7340032u; }
  *(f16x8*)(dst + off) = cvt8(src + off);
}

// ---- QKV GEMM big path: pipelined, C[4096,3072] = Xh @ Wh^T ---------------
__global__ __launch_bounds__(256) void gemm_qkv_p(
    const _Float16* __restrict__ Xh, const _Float16* __restrict__ Wh,
    _Float16* __restrict__ Qh, _Float16* __restrict__ Kh,
    _Float16* __restrict__ Vth) {
  __shared__ _Float16 As[128 * 72];
  __shared__ _Float16 Bs[128 * 72];
  const int tid = threadIdx.x;
  const int wave = tid >> 6, lane = tid & 63;
  const int quad = lane >> 4, l16 = lane & 15;
  const int wm = (wave >> 1) * 64, wn = (wave & 1) * 64;
  const int bn = blockIdx.x, bm = blockIdx.y;    // XCD = bn%8
  const int mat = bn >> 3;                       // 0=Q 1=K 2=V (block-uniform)

  // per-thread staging addresses (row/c8 fixed across K)
  const int row = tid >> 1;                      // 0..127 (2 threads/row)
  const int c32 = (tid & 1) * 32;                // half-row of 64: 4 int4 each
  const _Float16* gA = &Xh[(size_t)(bm * 128 + row) * 1024 + c32];
  const _Float16* gB = &Wh[(size_t)(bn * 128 + row) * 1024 + c32];
  _Float16* sA = &As[row * 72 + c32];
  _Float16* sB = &Bs[row * 72 + c32];

  int4 pa[4], pb[4];
#pragma unroll
  for (int j = 0; j < 4; ++j) {
    pa[j] = *(const int4*)(gA + j * 8);
    pb[j] = *(const int4*)(gB + j * 8);
  }

  f32x4 acc[4][4] = {};

  for (int k0 = 0; k0 < 1024; k0 += 64) {
    __syncthreads();
#pragma unroll
    for (int j = 0; j < 4; ++j) {
      *(int4*)(sA + j * 8) = pa[j];
      *(int4*)(sB + j * 8) = pb[j];
    }
    if (k0 < 960) {                              // prefetch tile k+1
#pragma unroll
      for (int j = 0; j < 4; ++j) {
        pa[j] = *(const int4*)(gA + k0 + 64 + j * 8);
        pb[j] = *(const int4*)(gB + k0 + 64 + j * 8);
      }
    }
    __syncthreads();
#pragma unroll
    for (int kc = 0; kc < 2; ++kc) {
      f16x8 af[4], bf[4];
#pragma unroll
      for (int t = 0; t < 4; ++t) {
        af[t] = *(const f16x8*)&As[(wm + t * 16 + l16) * 72 + kc * 32 + quad * 8];
        bf[t] = *(const f16x8*)&Bs[(wn + t * 16 + l16) * 72 + kc * 32 + quad * 8];
      }
#pragma unroll
      for (int mt = 0; mt < 4; ++mt)
#pragma unroll
        for (int nt = 0; nt < 4; ++nt)
          acc[mt][nt] = MFMA16(af[mt], bf[nt], acc[mt][nt]);
    }
  }

  // C-layout: col = l16, row = quad*4 + r  [verified m89/m91]
#pragma unroll
  for (int mt = 0; mt < 4; ++mt) {
    int m_base = bm * 128 + wm + mt * 16 + quad * 4;
    int b = m_base >> 11, sb = m_base & 2047;
#pragma unroll
    for (int nt = 0; nt < 4; ++nt) {
      int ob = (bn * 128 + wn + nt * 16) & 1023;
      int h = ob >> 6;
      int dh = (ob & 63) + l16;
      size_t bh = (size_t)(b * 16 + h);
      if (mat == 0) {
#pragma unroll
        for (int r = 0; r < 4; ++r)
          Qh[(bh * 2048 + sb + r) * 64 + dh] = (_Float16)(acc[mt][nt][r] * QSCALE);
      } else if (mat == 1) {
#pragma unroll
        for (int r = 0; r < 4; ++r)
          Kh[(bh * 2048 + sb + r) * 64 + dh] = (_Float16)acc[mt][nt][r];
      } else {
        f16x4 pk;
        pk[0] = (_Float16)acc[mt][nt][0];
        pk[1] = (_Float16)acc[mt][nt][1];
        pk[2] = (_Float16)acc[mt][nt][2];
        pk[3] = (_Float16)acc[mt][nt][3];
        *(f16x4*)&Vth[(bh * 64 + dh) * 2048 + sb] = pk;
      }
    }
  }
}

// ---- QKV GEMM fallback (ws too small): R5 path, cvt in-loop --------------
__global__ __launch_bounds__(256) void gemm_qkv_f(
    const _Float16* __restrict__ Xh, const float* __restrict__ Wq,
    const float* __restrict__ Wk, const float* __restrict__ Wv,
    _Float16* __restrict__ Qh, _Float16* __restrict__ Kh,
    _Float16* __restrict__ Vth) {
  __shared__ _Float16 As[128 * 72];
  __shared__ _Float16 Bs[128 * 72];
  const int tid = threadIdx.x;
  const int wave = tid >> 6, lane = tid & 63;
  const int quad = lane >> 4, l16 = lane & 15;
  const int wm = (wave >> 1) * 64, wn = (wave & 1) * 64;
  const int bn = blockIdx.x, bm = blockIdx.y;
  const int mat = bn >> 3;
  const float* Bsrc = (mat == 0) ? Wq : (mat == 1) ? Wk : Wv;
  const int brow0 = (bn & 7) * 128;

  f32x4 acc[4][4] = {};

  for (int k0 = 0; k0 < 1024; k0 += 64) {
    __syncthreads();
#pragma unroll
    for (int j = 0; j < 4; ++j) {
      int idx = tid + j * 256;
      int row = idx >> 3, c8 = idx & 7;
      *(int4*)&As[row * 72 + c8 * 8] =
          *(const int4*)&Xh[(size_t)(bm * 128 + row) * 1024 + k0 + c8 * 8];
      *(f16x8*)&Bs[row * 72 + c8 * 8] =
          cvt8(&Bsrc[(size_t)(brow0 + row) * 1024 + k0 + c8 * 8]);
    }
    __syncthreads();
#pragma unroll
    for (int kc = 0; kc < 2; ++kc) {
      f16x8 af[4], bf[4];
#pragma unroll
      for (int t = 0; t < 4; ++t) {
        af[t] = *(const f16x8*)&As[(wm + t * 16 + l16) * 72 + kc * 32 + quad * 8];
        bf[t] = *(const f16x8*)&Bs[(wn + t * 16 + l16) * 72 + kc * 32 + quad * 8];
      }
#pragma unroll
      for (int mt = 0; mt < 4; ++mt)
#pragma unroll
        for (int nt = 0; nt < 4; ++nt)
          acc[mt][nt] = MFMA16(af[mt], bf[nt], acc[mt][nt]);
    }
  }

#pragma unroll
  for (int mt = 0; mt < 4; ++mt) {
    int m_base = bm * 128 + wm + mt * 16 + quad * 4;
    int b = m_base >> 11, sb = m_base & 2047;
#pragma unroll
    for (int nt = 0; nt < 4; ++nt) {
      int ob = (bn * 128 + wn + nt * 16) & 1023;
      int h = ob >> 6;
      int dh = (ob & 63) + l16;
      size_t bh = (size_t)(b * 16 + h);
      if (mat == 0) {
#pragma unroll
        for (int r = 0; r < 4; ++r)
          Qh[(bh * 2048 + sb + r) * 64 + dh] = (_Float16)(acc[mt][nt][r] * QSCALE);
      } else if (mat == 1) {
#pragma unroll
        for (int r = 0; r < 4; ++r)
          Kh[(bh * 2048 + sb + r) * 64 + dh] = (_Float16)acc[mt][nt][r];
      } else {
        f16x4 pk;
        pk[0] = (_Float16)acc[mt][nt][0];
        pk[1] = (_Float16)acc[mt][nt][1];
        pk[2] = (_Float16)acc[mt][nt][2];
        pk[3] = (_Float16)acc[mt][nt][3];
        *(f16x4*)&Vth[(bh * 64 + dh) * 2048 + sb] = pk;
      }
    }
  }
}

// ---- attention R9 (unchanged): 512 thr, 2 groups x 4 waves, kt%2==group ---
__global__ __launch_bounds__(512) void attn_kernel(
    const _Float16* __restrict__ Qg, const _Float16* __restrict__ Kg,
    const _Float16* __restrict__ Vtg, _Float16* __restrict__ Og) {
  __shared__ _Float16 smem[2 * (128 * 72 + 64 * 136)];   // 71,680 B
  const int bh = blockIdx.x;               // XCD = bh % 8
  const int qt = 15 - (int)blockIdx.y;     // heavy tiles dispatched first
  const int q0 = qt * 128;
  const int tid = threadIdx.x;
  const int group = tid >> 8;
  const int tidg = tid & 255;
  const int wv = (tid >> 6) & 3;
  const int lane = tid & 63;
  const int l31 = lane & 31, hl = lane >> 5;
  const int b = bh >> 4, h = bh & 15;
  const int qrow = q0 + wv * 32 + l31;

  _Float16* Kl = smem + group * (128 * 72 + 64 * 136);
  _Float16* Vl = Kl + 128 * 72;

  const _Float16* Qbase = Qg + ((size_t)bh * 2048 + qrow) * 64 + hl * 8;
  f16x8 aq[4];
#pragma unroll
  for (int t = 0; t < 4; ++t) aq[t] = *(const f16x8*)(Qbase + 16 * t);

  f32x16 oacc[2] = {};
  float lsum = 0.f;

  const int nmax = (qt + 2) >> 1;
  for (int it = 0; it < nmax; ++it) {
    const int kt = 2 * it + group;
    const bool valid = (kt <= qt);
    const int k0 = kt << 7;
    __syncthreads();
    if (valid) {
#pragma unroll
      for (int i = tidg; i < 1024; i += 256) {
        int row = i >> 3, c8 = i & 7;
        *(int4*)&Kl[row * 72 + c8 * 8] =
            *(const int4*)&Kg[((size_t)bh * 2048 + k0 + row) * 64 + c8 * 8];
      }
#pragma unroll
      for (int i = tidg; i < 1024; i += 256) {
        int row = i >> 4, c16 = i & 15;
        *(int4*)&Vl[row * 136 + c16 * 8] =
            *(const int4*)&Vtg[((size_t)bh * 64 + row) * 2048 + k0 + c16 * 8];
      }
    }
    __syncthreads();
    if (!valid) continue;

    const bool diag = (kt == qt);

#pragma unroll
    for (int s32t = 0; s32t < 4; ++s32t) {
      f32x16 tv = {};
#pragma unroll
      for (int t = 0; t < 4; ++t) {
        f16x8 kb = *(const f16x8*)&Kl[(s32t * 32 + l31) * 72 + t * 16 + hl * 8];
        tv = MFMA32(kb, aq[t], tv);
      }
      int pkx[8];
#pragma unroll
      for (int i = 0; i < 8; ++i) {
        float x0 = tv[2 * i], x1 = tv[2 * i + 1];
        int kg = k0 + s32t * 32 + ((2 * i) & 3) + 8 * (i >> 1) + 4 * hl;
        if (diag) {
          if (kg > qrow) x0 = -1e30f;
          if (kg + 1 > qrow) x1 = -1e30f;
        }
        x0 = __builtin_amdgcn_exp2f(x0);
        x1 = __builtin_amdgcn_exp2f(x1);
        lsum += x0 + x1;
        pkx[i] = __builtin_bit_cast(int, pk2(x0, x1));
      }
      int s0 = hl ? pkx[0] : pkx[2];
      int s1 = hl ? pkx[1] : pkx[3];
      int s2 = hl ? pkx[4] : pkx[6];
      int s3 = hl ? pkx[5] : pkx[7];
      int r0 = __shfl_xor(s0, 32);
      int r1 = __shfl_xor(s1, 32);
      int r2 = __shfl_xor(s2, 32);
      int r3 = __shfl_xor(s3, 32);
      int4 f0, f1;
      f0.x = hl ? r0 : pkx[0];
      f0.y = hl ? r1 : pkx[1];
      f0.z = hl ? pkx[2] : r0;
      f0.w = hl ? pkx[3] : r1;
      f1.x = hl ? r2 : pkx[4];
      f1.y = hl ? r3 : pkx[5];
      f1.z = hl ? pkx[6] : r2;
      f1.w = hl ? pkx[7] : r3;
      f16x8 bp0 = __builtin_bit_cast(f16x8, f0);
      f16x8 bp1 = __builtin_bit_cast(f16x8, f1);
#pragma unroll
      for (int d = 0; d < 2; ++d) {
        f16x8 vb0 = *(const f16x8*)&Vl[(d * 32 + l31) * 136 + s32t * 32 + hl * 8];
        f16x8 vb1 =
            *(const f16x8*)&Vl[(d * 32 + l31) * 136 + s32t * 32 + 16 + hl * 8];
        oacc[d] = MFMA32(vb0, bp0, oacc[d]);
        oacc[d] = MFMA32(vb1, bp1, oacc[d]);
      }
    }
  }

  __syncthreads();
  float* mbuf = (float*)(smem + (128 * 72 + 64 * 136));
  float* slot = mbuf + (wv * 64 + lane) * 33;
  if (group == 1) {
#pragma unroll
    for (int d = 0; d < 2; ++d)
#pragma unroll
      for (int j = 0; j < 16; ++j) slot[d * 16 + j] = oacc[d][j];
    slot[32] = lsum;
  }
  __syncthreads();
  if (group == 0) {
#pragma unroll
    for (int d = 0; d < 2; ++d)
#pragma unroll
      for (int j = 0; j < 16; ++j) oacc[d][j] += slot[d * 16 + j];
    lsum += slot[32];
    lsum += __shfl_xor(lsum, 32);
    float inv = 1.0f / lsum;
#pragma unroll
    for (int d = 0; d < 2; ++d)
#pragma unroll
      for (int rq = 0; rq < 4; ++rq) {
        f16x4 o;
#pragma unroll
        for (int j = 0; j < 4; ++j)
          o[j] = (_Float16)(oacc[d][rq * 4 + j] * inv);
        int dh = d * 32 + 8 * rq + 4 * hl;
        *(f16x4*)&Og[(((size_t)b * 2048 + qrow) * 16 + h) * 64 + dh] = o;
      }
  }
}

// ---- output GEMM big path: pipelined, 128x64 tiles ------------------------
__global__ __launch_bounds__(256) void gemm_out_p(
    const _Float16* __restrict__ A, const _Float16* __restrict__ Woh,
    float* __restrict__ Co) {
  __shared__ _Float16 As[128 * 72];
  __shared__ _Float16 Bs[64 * 72];
  const int tid = threadIdx.x;
  const int wave = tid >> 6, lane = tid & 63;
  const int quad = lane >> 4, l16 = lane & 15;
  const int wm = (wave >> 1) * 64, wn = (wave & 1) * 32;
  const int bn = blockIdx.x, bm = blockIdx.y;

  const int rowA = tid >> 1;
  const int c32A = (tid & 1) * 32;
  const _Float16* gA = &A[(size_t)(bm * 128 + rowA) * 1024 + c32A];
  _Float16* sA = &As[rowA * 72 + c32A];
  const int rowB = tid >> 2;                 // 0..63 (4 threads/row)
  const int c16B = (tid & 3) * 16;           // 2 int4 each
  const _Float16* gB = &Woh[(size_t)(bn * 64 + rowB) * 1024 + c16B];
  _Float16* sB = &Bs[rowB * 72 + c16B];

  int4 pa[4], pb[2];
#pragma unroll
  for (int j = 0; j < 4; ++j) pa[j] = *(const int4*)(gA + j * 8);
#pragma unroll
  for (int j = 0; j < 2; ++j) pb[j] = *(const int4*)(gB + j * 8);

  f32x4 acc[4][2] = {};

  for (int k0 = 0; k0 < 1024; k0 += 64) {
    __syncthreads();
#pragma unroll
    for (int j = 0; j < 4; ++j) *(int4*)(sA + j * 8) = pa[j];
#pragma unroll
    for (int j = 0; j < 2; ++j) *(int4*)(sB + j * 8) = pb[j];
    if (k0 < 960) {
#pragma unroll
      for (int j = 0; j < 4; ++j) pa[j] = *(const int4*)(gA + k0 + 64 + j * 8);
#pragma unroll
      for (int j = 0; j < 2; ++j) pb[j] = *(const int4*)(gB + k0 + 64 + j * 8);
    }
    __syncthreads();
#pragma unroll
    for (int kc = 0; kc < 2; ++kc) {
      f16x8 af[4], bf[2];
#pragma unroll
      for (int t = 0; t < 4; ++t)
        af[t] = *(const f16x8*)&As[(wm + t * 16 + l16) * 72 + kc * 32 + quad * 8];
#pragma unroll
      for (int t = 0; t < 2; ++t)
        bf[t] = *(const f16x8*)&Bs[(wn + t * 16 + l16) * 72 + kc * 32 + quad * 8];
#pragma unroll
      for (int mt = 0; mt < 4; ++mt)
#pragma unroll
        for (int nt = 0; nt < 2; ++nt)
          acc[mt][nt] = MFMA16(af[mt], bf[nt], acc[mt][nt]);
    }
  }

#pragma unroll
  for (int mt = 0; mt < 4; ++mt) {
    int m_base = bm * 128 + wm + mt * 16 + quad * 4;
#pragma unroll
    for (int nt = 0; nt < 2; ++nt) {
      int n = bn * 64 + wn + nt * 16 + l16;
#pragma unroll
      for (int r = 0; r < 4; ++r)
        Co[(size_t)(m_base + r) * 1024 + n] = acc[mt][nt][r];
    }
  }
}

// ---- output GEMM fallback: cvt in-loop ------------------------------------
__global__ __launch_bounds__(256) void gemm_out_f(
    const _Float16* __restrict__ A, const float* __restrict__ Wo,
    float* __restrict__ Co) {
  __shared__ _Float16 As[128 * 72];
  __shared__ _Float16 Bs[64 * 72];
  const int tid = threadIdx.x;
  const int wave = tid >> 6, lane = tid & 63;
  const int quad = lane >> 4, l16 = lane & 15;
  const int wm = (wave >> 1) * 64, wn = (wave & 1) * 32;
  const int bn = blockIdx.x, bm = blockIdx.y;

  f32x4 acc[4][2] = {};

  for (int k0 = 0; k0 < 1024; k0 += 64) {
    __syncthreads();
#pragma unroll
    for (int j = 0; j < 4; ++j) {
      int idx = tid + j * 256;
      int row = idx >> 3, c8 = idx & 7;
      *(int4*)&As[row * 72 + c8 * 8] =
          *(const int4*)&A[(size_t)(bm * 128 + row) * 1024 + k0 + c8 * 8];
    }
#pragma unroll
    for (int j = 0; j < 2; ++j) {
      int idx = tid + j * 256;
      int row = idx >> 3, c8 = idx & 7;
      *(f16x8*)&Bs[row * 72 + c8 * 8] =
          cvt8(&Wo[(size_t)(bn * 64 + row) * 1024 + k0 + c8 * 8]);
    }
    __syncthreads();
#pragma unroll
    for (int kc = 0; kc < 2; ++kc) {
      f16x8 af[4], bf[2];
#pragma unroll
      for (int t = 0; t < 4; ++t)
        af[t] = *(const f16x8*)&As[(wm + t * 16 + l16) * 72 + kc * 32 + quad * 8];
#pragma unroll
      for (int t = 0; t < 2; ++t)
        bf[t] = *(const f16x8*)&Bs[(wn + t * 16 + l16) * 72 + kc * 32 + quad * 8];
#pragma unroll
      for (int mt = 0; mt < 4; ++mt)
#pragma unroll
        for (int nt = 0; nt < 2; ++nt)
          acc[mt][nt] = MFMA16(af[mt], bf[nt], acc[mt][nt]);
    }
  }

#pragma unroll
  for (int mt = 0; mt < 4; ++mt) {
    int m_base = bm * 128 + wm + mt * 16 + quad * 4;
#pragma unroll
    for (int nt = 0; nt < 2; ++nt) {
      int n = bn * 64 + wn + nt * 16 + l16;
#pragma unroll
      for (int r = 0; r < 4; ++r)
        Co[(size_t)(m_base + r) * 1024 + n] = acc[mt][nt][r];
    }
  }
}

extern "C" void kernel_launch(void* const* d_in, const int* in_sizes, int n_in,
                              void* d_out, int out_size, void* d_ws, size_t ws_size,
                              hipStream_t stream) {
  const float* X  = (const float*)d_in[0];
  const float* Wq = (const float*)d_in[1];
  const float* Wk = (const float*)d_in[2];
  const float* Wv = (const float*)d_in[3];
  const float* Wo = (const float*)d_in[4];
  float* out = (float*)d_out;

  _Float16* Qh    = (_Float16*)d_out;        // 4M halves (d_out scratch)
  _Float16* Kh    = Qh + 4194304;            // 4M halves
  _Float16* Vth   = (_Float16*)d_ws;         // 4M halves [b,h,dh,s]
  _Float16* Xh    = Vth + 4194304;           // 4M halves (Og overlay)
  _Float16* Og    = Xh;
  _Float16* Wqkvh = Xh + 4194304;            // 3M halves (big path only)
  _Float16* Woh   = Wqkvh + 3145728;         // 1M halves

  const bool big = (ws_size >= 25165824u);

  convert_all<<<big ? 4096 : 2048, 256, 0, stream>>>(X, Wq, Wk, Wv, Wo,
                                                     Xh, Wqkvh, Woh);
  if (big)
    gemm_qkv_p<<<dim3(24, 32), 256, 0, stream>>>(Xh, Wqkvh, Qh, Kh, Vth);
  else
    gemm_qkv_f<<<dim3(24, 32), 256, 0, stream>>>(Xh, Wq, Wk, Wv, Qh, Kh, Vth);
  attn_kernel<<<dim3(32, 16), 512, 0, stream>>>(Qh, Kh, Vth, Og);
  if (big)
    gemm_out_p<<<dim3(16, 32), 256, 0, stream>>>(Og, Woh, out);
  else
    gemm_out_f<<<dim3(16, 32), 256, 0, stream>>>(Og, Wo, out);
}

// Round 11
// 189.485 us; speedup vs baseline: 1.5826x; 1.5826x over previous
//
#include <hip/hip_runtime.h>
#include <math.h>

// ---------------------------------------------------------------------------
// Attn_14920716386547 R11 = R9 (184.2 us) with smaller GEMM tiles for more
// block-streams/CU. R10 post-mortem: VGPR-prefetch pipelining spilled to
// scratch (WRITE_SIZE 409 MB, 130 us) -> reverted entirely.
// R9 diagnosis stands: gemm_qkv phases are naked-latency-bound and GRID
// limited (768 blocks = 3/CU). R11: qkv 64x128 tiles -> 1536 blocks = 6/CU
// (LDS 27.6 KB); out 64x64 tiles -> 1024 blocks = 4/CU. Attn unchanged.
// ws (halves): Vth [0,4M) | Xh/Og overlay [4M,8M) | Wqkvh [8M,11M) |
//   Woh [11M,12M) (big path only). d_out: Qh|Kh scratch (dead before out).
// ---------------------------------------------------------------------------

typedef _Float16 f16x8 __attribute__((ext_vector_type(8)));
typedef _Float16 f16x4 __attribute__((ext_vector_type(4)));
typedef _Float16 f16x2 __attribute__((ext_vector_type(2)));
typedef __attribute__((ext_vector_type(4))) float f32x4;
typedef __attribute__((ext_vector_type(16))) float f32x16;

#define MFMA16(a, b, c) __builtin_amdgcn_mfma_f32_16x16x32_f16(a, b, c, 0, 0, 0)
#define MFMA32(a, b, c) __builtin_amdgcn_mfma_f32_32x32x16_f16(a, b, c, 0, 0, 0)
#define QSCALE 0.18033688f /* 0.125 * log2(e): attention runs in exp2 domain */

__device__ __forceinline__ f16x2 pk2(float x, float y) {
  return __builtin_bit_cast(f16x2, __builtin_amdgcn_cvt_pkrtz(x, y));
}

__device__ __forceinline__ f16x8 cvt8(const float* __restrict__ p) {
  float4 a = *(const float4*)p;
  float4 b = *(const float4*)(p + 4);
  f16x2 p0 = pk2(a.x, a.y), p1 = pk2(a.z, a.w);
  f16x2 p2 = pk2(b.x, b.y), p3 = pk2(b.z, b.w);
  f16x8 h;
  h[0] = p0[0]; h[1] = p0[1]; h[2] = p1[0]; h[3] = p1[1];
  h[4] = p2[0]; h[5] = p2[1]; h[6] = p3[0]; h[7] = p3[1];
  return h;
}

// ---- fp32 -> fp16 convert: X always; with grid=4096 also Wq|Wk|Wv|Wo ------
__global__ void convert_all(const float* __restrict__ X, const float* __restrict__ Wq,
                            const float* __restrict__ Wk, const float* __restrict__ Wv,
                            const float* __restrict__ Wo, _Float16* __restrict__ Xh,
                            _Float16* __restrict__ Wqkvh, _Float16* __restrict__ Woh) {
  size_t i = ((size_t)blockIdx.x * 256 + threadIdx.x) * 8;
  const float* src; _Float16* dst; size_t off;
  if (i < 4194304u)      { src = X;  dst = Xh;              off = i; }
  else if (i < 5242880u) { src = Wq; dst = Wqkvh;           off = i - 4194304u; }
  else if (i < 6291456u) { src = Wk; dst = Wqkvh + 1048576; off = i - 5242880u; }
  else if (i < 7340032u) { src = Wv; dst = Wqkvh + 2097152; off = i - 6291456u; }
  else                   { src = Wo; dst = Woh;             off = i - 7340032u; }
  *(f16x8*)(dst + off) = cvt8(src + off);
}

// ---- QKV GEMM: 64x128 tiles, 1536 blocks (6/CU). C = Xh @ W^T -------------
// Wave w: rows 0..63, cols w*32..w*32+31 -> acc[4][2].
template <int BH>
__global__ __launch_bounds__(256) void gemm_qkv(
    const _Float16* __restrict__ Xh, const float* __restrict__ Wq,
    const float* __restrict__ Wk, const float* __restrict__ Wv,
    const _Float16* __restrict__ Wh, _Float16* __restrict__ Qh,
    _Float16* __restrict__ Kh, _Float16* __restrict__ Vth) {
  __shared__ _Float16 As[64 * 72];
  __shared__ _Float16 Bs[128 * 72];
  const int tid = threadIdx.x;
  const int wave = tid >> 6, lane = tid & 63;
  const int quad = lane >> 4, l16 = lane & 15;
  const int wn = wave * 32;
  const int bn = blockIdx.x, bm = blockIdx.y;    // bn 0..23, bm 0..63
  const int mat = bn >> 3;                       // 0=Q 1=K 2=V (block-uniform)
  const float* Bsrc = (mat == 0) ? Wq : (mat == 1) ? Wk : Wv;
  const int brow0 = (bn & 7) * 128;

  f32x4 acc[4][2] = {};

  for (int k0 = 0; k0 < 1024; k0 += 64) {
    __syncthreads();
#pragma unroll
    for (int j = 0; j < 2; ++j) {                // A: 64x64 = 512 chunks
      int idx = tid + j * 256;
      int row = idx >> 3, c8 = idx & 7;
      *(int4*)&As[row * 72 + c8 * 8] =
          *(const int4*)&Xh[(size_t)(bm * 64 + row) * 1024 + k0 + c8 * 8];
    }
#pragma unroll
    for (int j = 0; j < 4; ++j) {                // B: 128x64 = 1024 chunks
      int idx = tid + j * 256;
      int row = idx >> 3, c8 = idx & 7;
      if (BH)
        *(int4*)&Bs[row * 72 + c8 * 8] =
            *(const int4*)&Wh[(size_t)(bn * 128 + row) * 1024 + k0 + c8 * 8];
      else
        *(f16x8*)&Bs[row * 72 + c8 * 8] =
            cvt8(&Bsrc[(size_t)(brow0 + row) * 1024 + k0 + c8 * 8]);
    }
    __syncthreads();
#pragma unroll
    for (int kc = 0; kc < 2; ++kc) {
      f16x8 af[4], bf[2];
#pragma unroll
      for (int t = 0; t < 4; ++t)
        af[t] = *(const f16x8*)&As[(t * 16 + l16) * 72 + kc * 32 + quad * 8];
#pragma unroll
      for (int t = 0; t < 2; ++t)
        bf[t] = *(const f16x8*)&Bs[(wn + t * 16 + l16) * 72 + kc * 32 + quad * 8];
#pragma unroll
      for (int mt = 0; mt < 4; ++mt)
#pragma unroll
        for (int nt = 0; nt < 2; ++nt)
          acc[mt][nt] = MFMA16(af[mt], bf[nt], acc[mt][nt]);
    }
  }

  // C-layout: col = l16, row = quad*4 + r  [verified m89/m91]
#pragma unroll
  for (int mt = 0; mt < 4; ++mt) {
    int m_base = bm * 64 + mt * 16 + quad * 4;
    int b = m_base >> 11, sb = m_base & 2047;
#pragma unroll
    for (int nt = 0; nt < 2; ++nt) {
      int ob = (bn * 128 + wn + nt * 16) & 1023;
      int h = ob >> 6;
      int dh = (ob & 63) + l16;
      size_t bh = (size_t)(b * 16 + h);
      if (mat == 0) {
#pragma unroll
        for (int r = 0; r < 4; ++r)
          Qh[(bh * 2048 + sb + r) * 64 + dh] = (_Float16)(acc[mt][nt][r] * QSCALE);
      } else if (mat == 1) {
#pragma unroll
        for (int r = 0; r < 4; ++r)
          Kh[(bh * 2048 + sb + r) * 64 + dh] = (_Float16)acc[mt][nt][r];
      } else {
        f16x4 pk;
        pk[0] = (_Float16)acc[mt][nt][0];
        pk[1] = (_Float16)acc[mt][nt][1];
        pk[2] = (_Float16)acc[mt][nt][2];
        pk[3] = (_Float16)acc[mt][nt][3];
        *(f16x4*)&Vth[(bh * 64 + dh) * 2048 + sb] = pk;
      }
    }
  }
}

// ---- attention R9 (unchanged): 512 thr, 2 groups x 4 waves, kt%2==group ---
__global__ __launch_bounds__(512) void attn_kernel(
    const _Float16* __restrict__ Qg, const _Float16* __restrict__ Kg,
    const _Float16* __restrict__ Vtg, _Float16* __restrict__ Og) {
  __shared__ _Float16 smem[2 * (128 * 72 + 64 * 136)];   // 71,680 B
  const int bh = blockIdx.x;               // XCD = bh % 8
  const int qt = 15 - (int)blockIdx.y;     // heavy tiles dispatched first
  const int q0 = qt * 128;
  const int tid = threadIdx.x;
  const int group = tid >> 8;
  const int tidg = tid & 255;
  const int wv = (tid >> 6) & 3;
  const int lane = tid & 63;
  const int l31 = lane & 31, hl = lane >> 5;
  const int b = bh >> 4, h = bh & 15;
  const int qrow = q0 + wv * 32 + l31;

  _Float16* Kl = smem + group * (128 * 72 + 64 * 136);
  _Float16* Vl = Kl + 128 * 72;

  const _Float16* Qbase = Qg + ((size_t)bh * 2048 + qrow) * 64 + hl * 8;
  f16x8 aq[4];
#pragma unroll
  for (int t = 0; t < 4; ++t) aq[t] = *(const f16x8*)(Qbase + 16 * t);

  f32x16 oacc[2] = {};
  float lsum = 0.f;

  const int nmax = (qt + 2) >> 1;
  for (int it = 0; it < nmax; ++it) {
    const int kt = 2 * it + group;
    const bool valid = (kt <= qt);
    const int k0 = kt << 7;
    __syncthreads();
    if (valid) {
#pragma unroll
      for (int i = tidg; i < 1024; i += 256) {
        int row = i >> 3, c8 = i & 7;
        *(int4*)&Kl[row * 72 + c8 * 8] =
            *(const int4*)&Kg[((size_t)bh * 2048 + k0 + row) * 64 + c8 * 8];
      }
#pragma unroll
      for (int i = tidg; i < 1024; i += 256) {
        int row = i >> 4, c16 = i & 15;
        *(int4*)&Vl[row * 136 + c16 * 8] =
            *(const int4*)&Vtg[((size_t)bh * 64 + row) * 2048 + k0 + c16 * 8];
      }
    }
    __syncthreads();
    if (!valid) continue;

    const bool diag = (kt == qt);

#pragma unroll
    for (int s32t = 0; s32t < 4; ++s32t) {
      f32x16 tv = {};
#pragma unroll
      for (int t = 0; t < 4; ++t) {
        f16x8 kb = *(const f16x8*)&Kl[(s32t * 32 + l31) * 72 + t * 16 + hl * 8];
        tv = MFMA32(kb, aq[t], tv);
      }
      int pkx[8];
#pragma unroll
      for (int i = 0; i < 8; ++i) {
        float x0 = tv[2 * i], x1 = tv[2 * i + 1];
        int kg = k0 + s32t * 32 + ((2 * i) & 3) + 8 * (i >> 1) + 4 * hl;
        if (diag) {
          if (kg > qrow) x0 = -1e30f;
          if (kg + 1 > qrow) x1 = -1e30f;
        }
        x0 = __builtin_amdgcn_exp2f(x0);
        x1 = __builtin_amdgcn_exp2f(x1);
        lsum += x0 + x1;
        pkx[i] = __builtin_bit_cast(int, pk2(x0, x1));
      }
      int s0 = hl ? pkx[0] : pkx[2];
      int s1 = hl ? pkx[1] : pkx[3];
      int s2 = hl ? pkx[4] : pkx[6];
      int s3 = hl ? pkx[5] : pkx[7];
      int r0 = __shfl_xor(s0, 32);
      int r1 = __shfl_xor(s1, 32);
      int r2 = __shfl_xor(s2, 32);
      int r3 = __shfl_xor(s3, 32);
      int4 f0, f1;
      f0.x = hl ? r0 : pkx[0];
      f0.y = hl ? r1 : pkx[1];
      f0.z = hl ? pkx[2] : r0;
      f0.w = hl ? pkx[3] : r1;
      f1.x = hl ? r2 : pkx[4];
      f1.y = hl ? r3 : pkx[5];
      f1.z = hl ? pkx[6] : r2;
      f1.w = hl ? pkx[7] : r3;
      f16x8 bp0 = __builtin_bit_cast(f16x8, f0);
      f16x8 bp1 = __builtin_bit_cast(f16x8, f1);
#pragma unroll
      for (int d = 0; d < 2; ++d) {
        f16x8 vb0 = *(const f16x8*)&Vl[(d * 32 + l31) * 136 + s32t * 32 + hl * 8];
        f16x8 vb1 =
            *(const f16x8*)&Vl[(d * 32 + l31) * 136 + s32t * 32 + 16 + hl * 8];
        oacc[d] = MFMA32(vb0, bp0, oacc[d]);
        oacc[d] = MFMA32(vb1, bp1, oacc[d]);
      }
    }
  }

  __syncthreads();
  float* mbuf = (float*)(smem + (128 * 72 + 64 * 136));
  float* slot = mbuf + (wv * 64 + lane) * 33;
  if (group == 1) {
#pragma unroll
    for (int d = 0; d < 2; ++d)
#pragma unroll
      for (int j = 0; j < 16; ++j) slot[d * 16 + j] = oacc[d][j];
    slot[32] = lsum;
  }
  __syncthreads();
  if (group == 0) {
#pragma unroll
    for (int d = 0; d < 2; ++d)
#pragma unroll
      for (int j = 0; j < 16; ++j) oacc[d][j] += slot[d * 16 + j];
    lsum += slot[32];
    lsum += __shfl_xor(lsum, 32);
    float inv = 1.0f / lsum;
#pragma unroll
    for (int d = 0; d < 2; ++d)
#pragma unroll
      for (int rq = 0; rq < 4; ++rq) {
        f16x4 o;
#pragma unroll
        for (int j = 0; j < 4; ++j)
          o[j] = (_Float16)(oacc[d][rq * 4 + j] * inv);
        int dh = d * 32 + 8 * rq + 4 * hl;
        *(f16x4*)&Og[(((size_t)b * 2048 + qrow) * 16 + h) * 64 + dh] = o;
      }
  }
}

// ---- output GEMM: 64x64 tiles, 1024 blocks (4/CU). Waves 2x2 --------------
template <int BH>
__global__ __launch_bounds__(256) void gemm_out(
    const _Float16* __restrict__ A, const float* __restrict__ Wo,
    const _Float16* __restrict__ Woh, float* __restrict__ Co) {
  __shared__ _Float16 As[64 * 72];
  __shared__ _Float16 Bs[64 * 72];
  const int tid = threadIdx.x;
  const int wave = tid >> 6, lane = tid & 63;
  const int quad = lane >> 4, l16 = lane & 15;
  const int wm = (wave >> 1) * 32, wn = (wave & 1) * 32;
  const int bn = blockIdx.x, bm = blockIdx.y;   // bn 0..15, bm 0..63

  f32x4 acc[2][2] = {};

  for (int k0 = 0; k0 < 1024; k0 += 64) {
    __syncthreads();
#pragma unroll
    for (int j = 0; j < 2; ++j) {
      int idx = tid + j * 256;
      int row = idx >> 3, c8 = idx & 7;
      *(int4*)&As[row * 72 + c8 * 8] =
          *(const int4*)&A[(size_t)(bm * 64 + row) * 1024 + k0 + c8 * 8];
    }
#pragma unroll
    for (int j = 0; j < 2; ++j) {
      int idx = tid + j * 256;
      int row = idx >> 3, c8 = idx & 7;
      if (BH)
        *(int4*)&Bs[row * 72 + c8 * 8] =
            *(const int4*)&Woh[(size_t)(bn * 64 + row) * 1024 + k0 + c8 * 8];
      else
        *(f16x8*)&Bs[row * 72 + c8 * 8] =
            cvt8(&Wo[(size_t)(bn * 64 + row) * 1024 + k0 + c8 * 8]);
    }
    __syncthreads();
#pragma unroll
    for (int kc = 0; kc < 2; ++kc) {
      f16x8 af[2], bf[2];
#pragma unroll
      for (int t = 0; t < 2; ++t) {
        af[t] = *(const f16x8*)&As[(wm + t * 16 + l16) * 72 + kc * 32 + quad * 8];
        bf[t] = *(const f16x8*)&Bs[(wn + t * 16 + l16) * 72 + kc * 32 + quad * 8];
      }
#pragma unroll
      for (int mt = 0; mt < 2; ++mt)
#pragma unroll
        for (int nt = 0; nt < 2; ++nt)
          acc[mt][nt] = MFMA16(af[mt], bf[nt], acc[mt][nt]);
    }
  }

#pragma unroll
  for (int mt = 0; mt < 2; ++mt) {
    int m_base = bm * 64 + wm + mt * 16 + quad * 4;
#pragma unroll
    for (int nt = 0; nt < 2; ++nt) {
      int n = bn * 64 + wn + nt * 16 + l16;
#pragma unroll
      for (int r = 0; r < 4; ++r)
        Co[(size_t)(m_base + r) * 1024 + n] = acc[mt][nt][r];
    }
  }
}

extern "C" void kernel_launch(void* const* d_in, const int* in_sizes, int n_in,
                              void* d_out, int out_size, void* d_ws, size_t ws_size,
                              hipStream_t stream) {
  const float* X  = (const float*)d_in[0];
  const float* Wq = (const float*)d_in[1];
  const float* Wk = (const float*)d_in[2];
  const float* Wv = (const float*)d_in[3];
  const float* Wo = (const float*)d_in[4];
  float* out = (float*)d_out;

  _Float16* Qh    = (_Float16*)d_out;        // 4M halves (d_out scratch)
  _Float16* Kh    = Qh + 4194304;            // 4M halves
  _Float16* Vth   = (_Float16*)d_ws;         // 4M halves [b,h,dh,s]
  _Float16* Xh    = Vth + 4194304;           // 4M halves (Og overlay)
  _Float16* Og    = Xh;
  _Float16* Wqkvh = Xh + 4194304;            // 3M halves (big path only)
  _Float16* Woh   = Wqkvh + 3145728;         // 1M halves

  const bool big = (ws_size >= 25165824u);

  convert_all<<<big ? 4096 : 2048, 256, 0, stream>>>(X, Wq, Wk, Wv, Wo,
                                                     Xh, Wqkvh, Woh);
  if (big)
    gemm_qkv<1><<<dim3(24, 64), 256, 0, stream>>>(Xh, Wq, Wk, Wv, Wqkvh,
                                                  Qh, Kh, Vth);
  else
    gemm_qkv<0><<<dim3(24, 64), 256, 0, stream>>>(Xh, Wq, Wk, Wv, nullptr,
                                                  Qh, Kh, Vth);
  attn_kernel<<<dim3(32, 16), 512, 0, stream>>>(Qh, Kh, Vth, Og);
  if (big)
    gemm_out<1><<<dim3(16, 64), 256, 0, stream>>>(Og, Wo, Woh, out);
  else
    gemm_out<0><<<dim3(16, 64), 256, 0, stream>>>(Og, Wo, nullptr, out);
}

// Round 12
// 175.099 us; speedup vs baseline: 1.7126x; 1.0822x over previous
//
#include <hip/hip_runtime.h>
#include <math.h>

// ---------------------------------------------------------------------------
// Attn_14920716386547 R12 = R9 (184.2 us, best) with the big-path QKV GEMM
// replaced by the literal m97 recipe: 128x128 tile, BK=32, async
// global_load_lds(16B) staging, unpadded LDS (16 KB).
// R11 post-mortem: 6 blk/CU did NOT speed qkv (49.5 us both) -> limiter is
// per-CU shared (LDS traffic), not wave count; smaller tiles raised LDS
// bytes/FLOP 1.5x. Reverted. R10's VGPR prefetch spilled. The one proven
// lever not yet tried in its exact shape: m97 async staging (517->874 TF).
// ws (halves): Vth [0,4M) | Xh/Og overlay [4M,8M) | Wqkvh [8M,11M) |
//   Woh [11M,12M) (big path only). d_out: Qh|Kh scratch (dead before out).
// ---------------------------------------------------------------------------

typedef _Float16 f16x8 __attribute__((ext_vector_type(8)));
typedef _Float16 f16x4 __attribute__((ext_vector_type(4)));
typedef _Float16 f16x2 __attribute__((ext_vector_type(2)));
typedef __attribute__((ext_vector_type(4))) float f32x4;
typedef __attribute__((ext_vector_type(16))) float f32x16;

#define MFMA16(a, b, c) __builtin_amdgcn_mfma_f32_16x16x32_f16(a, b, c, 0, 0, 0)
#define MFMA32(a, b, c) __builtin_amdgcn_mfma_f32_32x32x16_f16(a, b, c, 0, 0, 0)
#define QSCALE 0.18033688f /* 0.125 * log2(e): attention runs in exp2 domain */

__device__ __forceinline__ void async16(const void* g, void* l) {
  // async global->LDS, 16 B/lane; l = wave-uniform base, lane scatters +16B
  __builtin_amdgcn_global_load_lds(
      (const __attribute__((address_space(1))) unsigned int*)g,
      (__attribute__((address_space(3))) unsigned int*)l, 16, 0, 0);
}

__device__ __forceinline__ f16x2 pk2(float x, float y) {
  return __builtin_bit_cast(f16x2, __builtin_amdgcn_cvt_pkrtz(x, y));
}

__device__ __forceinline__ f16x8 cvt8(const float* __restrict__ p) {
  float4 a = *(const float4*)p;
  float4 b = *(const float4*)(p + 4);
  f16x2 p0 = pk2(a.x, a.y), p1 = pk2(a.z, a.w);
  f16x2 p2 = pk2(b.x, b.y), p3 = pk2(b.z, b.w);
  f16x8 h;
  h[0] = p0[0]; h[1] = p0[1]; h[2] = p1[0]; h[3] = p1[1];
  h[4] = p2[0]; h[5] = p2[1]; h[6] = p3[0]; h[7] = p3[1];
  return h;
}

// ---- fp32 -> fp16 convert: X always; with grid=4096 also Wq|Wk|Wv|Wo ------
__global__ void convert_all(const float* __restrict__ X, const float* __restrict__ Wq,
                            const float* __restrict__ Wk, const float* __restrict__ Wv,
                            const float* __restrict__ Wo, _Float16* __restrict__ Xh,
                            _Float16* __restrict__ Wqkvh, _Float16* __restrict__ Woh) {
  size_t i = ((size_t)blockIdx.x * 256 + threadIdx.x) * 8;
  const float* src; _Float16* dst; size_t off;
  if (i < 4194304u)      { src = X;  dst = Xh;              off = i; }
  else if (i < 5242880u) { src = Wq; dst = Wqkvh;           off = i - 4194304u; }
  else if (i < 6291456u) { src = Wk; dst = Wqkvh + 1048576; off = i - 5242880u; }
  else if (i < 7340032u) { src = Wv; dst = Wqkvh + 2097152; off = i - 6291456u; }
  else                   { src = Wo; dst = Woh;             off = i - 7340032u; }
  *(f16x8*)(dst + off) = cvt8(src + off);
}

// ---- QKV GEMM big path: m97 recipe. 128x128, BK=32, async16, unpadded -----
__global__ __launch_bounds__(256) void gemm_qkv_a(
    const _Float16* __restrict__ Xh, const _Float16* __restrict__ Wh,
    _Float16* __restrict__ Qh, _Float16* __restrict__ Kh,
    _Float16* __restrict__ Vth) {
  __shared__ _Float16 As[128 * 32];   // unpadded (DMA dest), 8 KB
  __shared__ _Float16 Bs[128 * 32];
  const int tid = threadIdx.x;
  const int wave = tid >> 6, lane = tid & 63;
  const int quad = lane >> 4, l16 = lane & 15;
  const int wm = (wave >> 1) * 64, wn = (wave & 1) * 64;
  const int bn = blockIdx.x, bm = blockIdx.y;    // XCD = bn%8
  const int mat = bn >> 3;                       // 0=Q 1=K 2=V (block-uniform)

  // chunk c in [0,512): covers halves [c*8, c*8+8) = row c>>2, col (c&3)*8.
  // thread handles chunks tid and tid+256; wave-uniform LDS bases.
  const int r0 = tid >> 2, cc0 = (tid & 3) * 8;
  const int r1 = (tid + 256) >> 2, cc1 = (tid & 3) * 8;  // (tid+256)&3 == tid&3
  const _Float16* gA0 = &Xh[(size_t)(bm * 128 + r0) * 1024 + cc0];
  const _Float16* gA1 = &Xh[(size_t)(bm * 128 + r1) * 1024 + cc1];
  const _Float16* gB0 = &Wh[(size_t)(bn * 128 + r0) * 1024 + cc0];
  const _Float16* gB1 = &Wh[(size_t)(bn * 128 + r1) * 1024 + cc1];

  f32x4 acc[4][4] = {};

  for (int k0 = 0; k0 < 1024; k0 += 32) {
    __syncthreads();                     // all waves done reading prev tile
    async16(gA0 + k0, &As[(wave * 64) * 8]);
    async16(gA1 + k0, &As[(256 + wave * 64) * 8]);
    async16(gB0 + k0, &Bs[(wave * 64) * 8]);
    async16(gB1 + k0, &Bs[(256 + wave * 64) * 8]);
    __syncthreads();                     // vmcnt drain (compiler-inserted)
    f16x8 af[4], bf[4];
#pragma unroll
    for (int t = 0; t < 4; ++t) {
      af[t] = *(const f16x8*)&As[(wm + t * 16 + l16) * 32 + quad * 8];
      bf[t] = *(const f16x8*)&Bs[(wn + t * 16 + l16) * 32 + quad * 8];
    }
#pragma unroll
    for (int mt = 0; mt < 4; ++mt)
#pragma unroll
      for (int nt = 0; nt < 4; ++nt)
        acc[mt][nt] = MFMA16(af[mt], bf[nt], acc[mt][nt]);
  }

  // C-layout: col = l16, row = quad*4 + r  [verified m89/m91]
#pragma unroll
  for (int mt = 0; mt < 4; ++mt) {
    int m_base = bm * 128 + wm + mt * 16 + quad * 4;
    int b = m_base >> 11, sb = m_base & 2047;
#pragma unroll
    for (int nt = 0; nt < 4; ++nt) {
      int ob = (bn * 128 + wn + nt * 16) & 1023;
      int h = ob >> 6;
      int dh = (ob & 63) + l16;
      size_t bh = (size_t)(b * 16 + h);
      if (mat == 0) {
#pragma unroll
        for (int r = 0; r < 4; ++r)
          Qh[(bh * 2048 + sb + r) * 64 + dh] = (_Float16)(acc[mt][nt][r] * QSCALE);
      } else if (mat == 1) {
#pragma unroll
        for (int r = 0; r < 4; ++r)
          Kh[(bh * 2048 + sb + r) * 64 + dh] = (_Float16)acc[mt][nt][r];
      } else {
        f16x4 pk;
        pk[0] = (_Float16)acc[mt][nt][0];
        pk[1] = (_Float16)acc[mt][nt][1];
        pk[2] = (_Float16)acc[mt][nt][2];
        pk[3] = (_Float16)acc[mt][nt][3];
        *(f16x4*)&Vth[(bh * 64 + dh) * 2048 + sb] = pk;
      }
    }
  }
}

// ---- QKV GEMM fallback (small ws): R9 padded path, cvt in-loop ------------
__global__ __launch_bounds__(256) void gemm_qkv_f(
    const _Float16* __restrict__ Xh, const float* __restrict__ Wq,
    const float* __restrict__ Wk, const float* __restrict__ Wv,
    _Float16* __restrict__ Qh, _Float16* __restrict__ Kh,
    _Float16* __restrict__ Vth) {
  __shared__ _Float16 As[128 * 72];
  __shared__ _Float16 Bs[128 * 72];
  const int tid = threadIdx.x;
  const int wave = tid >> 6, lane = tid & 63;
  const int quad = lane >> 4, l16 = lane & 15;
  const int wm = (wave >> 1) * 64, wn = (wave & 1) * 64;
  const int bn = blockIdx.x, bm = blockIdx.y;
  const int mat = bn >> 3;
  const float* Bsrc = (mat == 0) ? Wq : (mat == 1) ? Wk : Wv;
  const int brow0 = (bn & 7) * 128;

  f32x4 acc[4][4] = {};

  for (int k0 = 0; k0 < 1024; k0 += 64) {
    __syncthreads();
#pragma unroll
    for (int j = 0; j < 4; ++j) {
      int idx = tid + j * 256;
      int row = idx >> 3, c8 = idx & 7;
      *(int4*)&As[row * 72 + c8 * 8] =
          *(const int4*)&Xh[(size_t)(bm * 128 + row) * 1024 + k0 + c8 * 8];
      *(f16x8*)&Bs[row * 72 + c8 * 8] =
          cvt8(&Bsrc[(size_t)(brow0 + row) * 1024 + k0 + c8 * 8]);
    }
    __syncthreads();
#pragma unroll
    for (int kc = 0; kc < 2; ++kc) {
      f16x8 af[4], bf[4];
#pragma unroll
      for (int t = 0; t < 4; ++t) {
        af[t] = *(const f16x8*)&As[(wm + t * 16 + l16) * 72 + kc * 32 + quad * 8];
        bf[t] = *(const f16x8*)&Bs[(wn + t * 16 + l16) * 72 + kc * 32 + quad * 8];
      }
#pragma unroll
      for (int mt = 0; mt < 4; ++mt)
#pragma unroll
        for (int nt = 0; nt < 4; ++nt)
          acc[mt][nt] = MFMA16(af[mt], bf[nt], acc[mt][nt]);
    }
  }

#pragma unroll
  for (int mt = 0; mt < 4; ++mt) {
    int m_base = bm * 128 + wm + mt * 16 + quad * 4;
    int b = m_base >> 11, sb = m_base & 2047;
#pragma unroll
    for (int nt = 0; nt < 4; ++nt) {
      int ob = (bn * 128 + wn + nt * 16) & 1023;
      int h = ob >> 6;
      int dh = (ob & 63) + l16;
      size_t bh = (size_t)(b * 16 + h);
      if (mat == 0) {
#pragma unroll
        for (int r = 0; r < 4; ++r)
          Qh[(bh * 2048 + sb + r) * 64 + dh] = (_Float16)(acc[mt][nt][r] * QSCALE);
      } else if (mat == 1) {
#pragma unroll
        for (int r = 0; r < 4; ++r)
          Kh[(bh * 2048 + sb + r) * 64 + dh] = (_Float16)acc[mt][nt][r];
      } else {
        f16x4 pk;
        pk[0] = (_Float16)acc[mt][nt][0];
        pk[1] = (_Float16)acc[mt][nt][1];
        pk[2] = (_Float16)acc[mt][nt][2];
        pk[3] = (_Float16)acc[mt][nt][3];
        *(f16x4*)&Vth[(bh * 64 + dh) * 2048 + sb] = pk;
      }
    }
  }
}

// ---- attention R9 (unchanged): 512 thr, 2 groups x 4 waves, kt%2==group ---
__global__ __launch_bounds__(512) void attn_kernel(
    const _Float16* __restrict__ Qg, const _Float16* __restrict__ Kg,
    const _Float16* __restrict__ Vtg, _Float16* __restrict__ Og) {
  __shared__ _Float16 smem[2 * (128 * 72 + 64 * 136)];   // 71,680 B
  const int bh = blockIdx.x;               // XCD = bh % 8
  const int qt = 15 - (int)blockIdx.y;     // heavy tiles dispatched first
  const int q0 = qt * 128;
  const int tid = threadIdx.x;
  const int group = tid >> 8;
  const int tidg = tid & 255;
  const int wv = (tid >> 6) & 3;
  const int lane = tid & 63;
  const int l31 = lane & 31, hl = lane >> 5;
  const int b = bh >> 4, h = bh & 15;
  const int qrow = q0 + wv * 32 + l31;

  _Float16* Kl = smem + group * (128 * 72 + 64 * 136);
  _Float16* Vl = Kl + 128 * 72;

  const _Float16* Qbase = Qg + ((size_t)bh * 2048 + qrow) * 64 + hl * 8;
  f16x8 aq[4];
#pragma unroll
  for (int t = 0; t < 4; ++t) aq[t] = *(const f16x8*)(Qbase + 16 * t);

  f32x16 oacc[2] = {};
  float lsum = 0.f;

  const int nmax = (qt + 2) >> 1;
  for (int it = 0; it < nmax; ++it) {
    const int kt = 2 * it + group;
    const bool valid = (kt <= qt);
    const int k0 = kt << 7;
    __syncthreads();
    if (valid) {
#pragma unroll
      for (int i = tidg; i < 1024; i += 256) {
        int row = i >> 3, c8 = i & 7;
        *(int4*)&Kl[row * 72 + c8 * 8] =
            *(const int4*)&Kg[((size_t)bh * 2048 + k0 + row) * 64 + c8 * 8];
      }
#pragma unroll
      for (int i = tidg; i < 1024; i += 256) {
        int row = i >> 4, c16 = i & 15;
        *(int4*)&Vl[row * 136 + c16 * 8] =
            *(const int4*)&Vtg[((size_t)bh * 64 + row) * 2048 + k0 + c16 * 8];
      }
    }
    __syncthreads();
    if (!valid) continue;

    const bool diag = (kt == qt);

#pragma unroll
    for (int s32t = 0; s32t < 4; ++s32t) {
      f32x16 tv = {};
#pragma unroll
      for (int t = 0; t < 4; ++t) {
        f16x8 kb = *(const f16x8*)&Kl[(s32t * 32 + l31) * 72 + t * 16 + hl * 8];
        tv = MFMA32(kb, aq[t], tv);
      }
      int pkx[8];
#pragma unroll
      for (int i = 0; i < 8; ++i) {
        float x0 = tv[2 * i], x1 = tv[2 * i + 1];
        int kg = k0 + s32t * 32 + ((2 * i) & 3) + 8 * (i >> 1) + 4 * hl;
        if (diag) {
          if (kg > qrow) x0 = -1e30f;
          if (kg + 1 > qrow) x1 = -1e30f;
        }
        x0 = __builtin_amdgcn_exp2f(x0);
        x1 = __builtin_amdgcn_exp2f(x1);
        lsum += x0 + x1;
        pkx[i] = __builtin_bit_cast(int, pk2(x0, x1));
      }
      int s0 = hl ? pkx[0] : pkx[2];
      int s1 = hl ? pkx[1] : pkx[3];
      int s2 = hl ? pkx[4] : pkx[6];
      int s3 = hl ? pkx[5] : pkx[7];
      int r0 = __shfl_xor(s0, 32);
      int r1 = __shfl_xor(s1, 32);
      int r2 = __shfl_xor(s2, 32);
      int r3 = __shfl_xor(s3, 32);
      int4 f0, f1;
      f0.x = hl ? r0 : pkx[0];
      f0.y = hl ? r1 : pkx[1];
      f0.z = hl ? pkx[2] : r0;
      f0.w = hl ? pkx[3] : r1;
      f1.x = hl ? r2 : pkx[4];
      f1.y = hl ? r3 : pkx[5];
      f1.z = hl ? pkx[6] : r2;
      f1.w = hl ? pkx[7] : r3;
      f16x8 bp0 = __builtin_bit_cast(f16x8, f0);
      f16x8 bp1 = __builtin_bit_cast(f16x8, f1);
#pragma unroll
      for (int d = 0; d < 2; ++d) {
        f16x8 vb0 = *(const f16x8*)&Vl[(d * 32 + l31) * 136 + s32t * 32 + hl * 8];
        f16x8 vb1 =
            *(const f16x8*)&Vl[(d * 32 + l31) * 136 + s32t * 32 + 16 + hl * 8];
        oacc[d] = MFMA32(vb0, bp0, oacc[d]);
        oacc[d] = MFMA32(vb1, bp1, oacc[d]);
      }
    }
  }

  __syncthreads();
  float* mbuf = (float*)(smem + (128 * 72 + 64 * 136));
  float* slot = mbuf + (wv * 64 + lane) * 33;
  if (group == 1) {
#pragma unroll
    for (int d = 0; d < 2; ++d)
#pragma unroll
      for (int j = 0; j < 16; ++j) slot[d * 16 + j] = oacc[d][j];
    slot[32] = lsum;
  }
  __syncthreads();
  if (group == 0) {
#pragma unroll
    for (int d = 0; d < 2; ++d)
#pragma unroll
      for (int j = 0; j < 16; ++j) oacc[d][j] += slot[d * 16 + j];
    lsum += slot[32];
    lsum += __shfl_xor(lsum, 32);
    float inv = 1.0f / lsum;
#pragma unroll
    for (int d = 0; d < 2; ++d)
#pragma unroll
      for (int rq = 0; rq < 4; ++rq) {
        f16x4 o;
#pragma unroll
        for (int j = 0; j < 4; ++j)
          o[j] = (_Float16)(oacc[d][rq * 4 + j] * inv);
        int dh = d * 32 + 8 * rq + 4 * hl;
        *(f16x4*)&Og[(((size_t)b * 2048 + qrow) * 16 + h) * 64 + dh] = o;
      }
  }
}

// ---- output GEMM (R9): 128x64 tiles, 512 blocks ---------------------------
template <int BH>
__global__ __launch_bounds__(256) void gemm_out(
    const _Float16* __restrict__ A, const float* __restrict__ Wo,
    const _Float16* __restrict__ Woh, float* __restrict__ Co) {
  __shared__ _Float16 As[128 * 72];
  __shared__ _Float16 Bs[64 * 72];
  const int tid = threadIdx.x;
  const int wave = tid >> 6, lane = tid & 63;
  const int quad = lane >> 4, l16 = lane & 15;
  const int wm = (wave >> 1) * 64, wn = (wave & 1) * 32;
  const int bn = blockIdx.x, bm = blockIdx.y;

  f32x4 acc[4][2] = {};

  for (int k0 = 0; k0 < 1024; k0 += 64) {
    __syncthreads();
#pragma unroll
    for (int j = 0; j < 4; ++j) {
      int idx = tid + j * 256;
      int row = idx >> 3, c8 = idx & 7;
      *(int4*)&As[row * 72 + c8 * 8] =
          *(const int4*)&A[(size_t)(bm * 128 + row) * 1024 + k0 + c8 * 8];
    }
#pragma unroll
    for (int j = 0; j < 2; ++j) {
      int idx = tid + j * 256;
      int row = idx >> 3, c8 = idx & 7;
      if (BH)
        *(int4*)&Bs[row * 72 + c8 * 8] =
            *(const int4*)&Woh[(size_t)(bn * 64 + row) * 1024 + k0 + c8 * 8];
      else
        *(f16x8*)&Bs[row * 72 + c8 * 8] =
            cvt8(&Wo[(size_t)(bn * 64 + row) * 1024 + k0 + c8 * 8]);
    }
    __syncthreads();
#pragma unroll
    for (int kc = 0; kc < 2; ++kc) {
      f16x8 af[4], bf[2];
#pragma unroll
      for (int t = 0; t < 4; ++t)
        af[t] = *(const f16x8*)&As[(wm + t * 16 + l16) * 72 + kc * 32 + quad * 8];
#pragma unroll
      for (int t = 0; t < 2; ++t)
        bf[t] = *(const f16x8*)&Bs[(wn + t * 16 + l16) * 72 + kc * 32 + quad * 8];
#pragma unroll
      for (int mt = 0; mt < 4; ++mt)
#pragma unroll
        for (int nt = 0; nt < 2; ++nt)
          acc[mt][nt] = MFMA16(af[mt], bf[nt], acc[mt][nt]);
    }
  }

#pragma unroll
  for (int mt = 0; mt < 4; ++mt) {
    int m_base = bm * 128 + wm + mt * 16 + quad * 4;
#pragma unroll
    for (int nt = 0; nt < 2; ++nt) {
      int n = bn * 64 + wn + nt * 16 + l16;
#pragma unroll
      for (int r = 0; r < 4; ++r)
        Co[(size_t)(m_base + r) * 1024 + n] = acc[mt][nt][r];
    }
  }
}

extern "C" void kernel_launch(void* const* d_in, const int* in_sizes, int n_in,
                              void* d_out, int out_size, void* d_ws, size_t ws_size,
                              hipStream_t stream) {
  const float* X  = (const float*)d_in[0];
  const float* Wq = (const float*)d_in[1];
  const float* Wk = (const float*)d_in[2];
  const float* Wv = (const float*)d_in[3];
  const float* Wo = (const float*)d_in[4];
  float* out = (float*)d_out;

  _Float16* Qh    = (_Float16*)d_out;        // 4M halves (d_out scratch)
  _Float16* Kh    = Qh + 4194304;            // 4M halves
  _Float16* Vth   = (_Float16*)d_ws;         // 4M halves [b,h,dh,s]
  _Float16* Xh    = Vth + 4194304;           // 4M halves (Og overlay)
  _Float16* Og    = Xh;
  _Float16* Wqkvh = Xh + 4194304;            // 3M halves (big path only)
  _Float16* Woh   = Wqkvh + 3145728;         // 1M halves

  const bool big = (ws_size >= 25165824u);

  convert_all<<<big ? 4096 : 2048, 256, 0, stream>>>(X, Wq, Wk, Wv, Wo,
                                                     Xh, Wqkvh, Woh);
  if (big)
    gemm_qkv_a<<<dim3(24, 32), 256, 0, stream>>>(Xh, Wqkvh, Qh, Kh, Vth);
  else
    gemm_qkv_f<<<dim3(24, 32), 256, 0, stream>>>(Xh, Wq, Wk, Wv, Qh, Kh, Vth);
  attn_kernel<<<dim3(32, 16), 512, 0, stream>>>(Qh, Kh, Vth, Og);
  if (big)
    gemm_out<1><<<dim3(16, 32), 256, 0, stream>>>(Og, Wo, Woh, out);
  else
    gemm_out<0><<<dim3(16, 32), 256, 0, stream>>>(Og, Wo, nullptr, out);
}